// Round 18
// baseline (840.168 us; speedup 1.0000x reference)
//
#include <hip/hip_runtime.h>
#include <hip/hip_bf16.h>
#include <cstdint>

#define DM 2048
#define DF 8192

typedef int v4i __attribute__((ext_vector_type(4)));
typedef int v16i __attribute__((ext_vector_type(16)));
typedef short v8s __attribute__((ext_vector_type(8)));

__device__ __forceinline__ float silu_f(float y) {
  return y * (1.0f / (1.0f + expf(-y)));
}

__device__ __forceinline__ void gload_lds16(const void* g, void* l) {
  __builtin_amdgcn_global_load_lds(
      (const __attribute__((address_space(1))) void*)g,
      (__attribute__((address_space(3))) void*)l, 16, 0, 0);
}

// ---- stage 1: sum |w| partials; blockIdx.y selects W1/W2 ----
__global__ __launch_bounds__(256) void abs_sum_k(const float* __restrict__ w1,
                                                 const float* __restrict__ w2,
                                                 float* __restrict__ partial) {
  const int t = threadIdx.x;
  const float* w = blockIdx.y ? w2 : w1;
  const float4* wp = (const float4*)w;
  const long base = (long)blockIdx.x * 4096;
  float s = 0.f;
#pragma unroll
  for (int i = 0; i < 16; ++i) {
    float4 v = wp[base + i * 256 + t];
    s += fabsf(v.x) + fabsf(v.y) + fabsf(v.z) + fabsf(v.w);
  }
#pragma unroll
  for (int d = 1; d < 64; d <<= 1) s += __shfl_xor(s, d, 64);
  __shared__ float wsum[4];
  if ((t & 63) == 0) wsum[t >> 6] = s;
  __syncthreads();
  if (t == 0) partial[blockIdx.y * 1024 + blockIdx.x] = (wsum[0] + wsum[1]) + (wsum[2] + wsum[3]);
}

// ---- stage 2: finalize weight scales ----
__global__ __launch_bounds__(256) void finalize_scales_k(const float* __restrict__ partial,
                                                         float* __restrict__ sc) {
  const float* p = partial + blockIdx.x * 1024;
  const int t = threadIdx.x;
  float s = (p[t] + p[t + 256]) + (p[t + 512] + p[t + 768]);
#pragma unroll
  for (int d = 1; d < 64; d <<= 1) s += __shfl_xor(s, d, 64);
  __shared__ float wsum[4];
  if ((t & 63) == 0) wsum[t >> 6] = s;
  __syncthreads();
  if (t == 0) {
    float total = (wsum[0] + wsum[1]) + (wsum[2] + wsum[3]);
    float mean = total * (1.0f / 16777216.0f);
    float c = fmaxf(mean, 1e-5f);
    sc[blockIdx.x * 2 + 0] = 1.0f / c;
    sc[blockIdx.x * 2 + 1] = c;
  }
}

// ---- ternary weight quantization; blockIdx.y selects W1/W2 ----
__global__ __launch_bounds__(256) void tern_quant_k(const float* __restrict__ w1,
                                                    const float* __restrict__ w2,
                                                    int8_t* __restrict__ wq1,
                                                    int8_t* __restrict__ wq2,
                                                    const float* __restrict__ sc) {
  const float* w = blockIdx.y ? w2 : w1;
  int8_t* wq = blockIdx.y ? wq2 : wq1;
  const float s = sc[blockIdx.y * 2];
  const long i = (long)blockIdx.x * 256 + threadIdx.x;
  float4 v = ((const float4*)w)[i];
  int q0 = (int)rintf(v.x * s); q0 = q0 < -1 ? -1 : (q0 > 1 ? 1 : q0);
  int q1 = (int)rintf(v.y * s); q1 = q1 < -1 ? -1 : (q1 > 1 ? 1 : q1);
  int q2 = (int)rintf(v.z * s); q2 = q2 < -1 ? -1 : (q2 > 1 ? 1 : q2);
  int q3 = (int)rintf(v.w * s); q3 = q3 < -1 ? -1 : (q3 > 1 ? 1 : q3);
  ((int*)wq)[i] = (q0 & 255) | ((q1 & 255) << 8) | ((q2 & 255) << 16) | ((q3 & 255) << 24);
}

// ---- per-token activation quant of x ----
__global__ __launch_bounds__(256) void act_quant_x_k(const float* __restrict__ x,
                                                     int8_t* __restrict__ xq,
                                                     float* __restrict__ inv_sx) {
  const int t = threadIdx.x;
  const long row = blockIdx.x;
  const float4* xr = (const float4*)(x + row * DM);
  float4 v0 = xr[t * 2], v1 = xr[t * 2 + 1];
  float m = fmaxf(fmaxf(fmaxf(fabsf(v0.x), fabsf(v0.y)), fmaxf(fabsf(v0.z), fabsf(v0.w))),
                  fmaxf(fmaxf(fabsf(v1.x), fabsf(v1.y)), fmaxf(fabsf(v1.z), fabsf(v1.w))));
#pragma unroll
  for (int d = 1; d < 64; d <<= 1) m = fmaxf(m, __shfl_xor(m, d, 64));
  __shared__ float wm[4];
  if ((t & 63) == 0) wm[t >> 6] = m;
  __syncthreads();
  m = fmaxf(fmaxf(wm[0], wm[1]), fmaxf(wm[2], wm[3]));
  const float scale = 127.0f / fmaxf(m, 1e-5f);
  if (t == 0) inv_sx[row] = 1.0f / scale;
  float vv[8] = {v0.x, v0.y, v0.z, v0.w, v1.x, v1.y, v1.z, v1.w};
  int q[8];
#pragma unroll
  for (int j = 0; j < 8; ++j) {
    int qq = (int)rintf(vv[j] * scale);
    q[j] = qq < -128 ? -128 : (qq > 127 ? 127 : qq);
  }
  int lo = (q[0] & 255) | ((q[1] & 255) << 8) | ((q[2] & 255) << 16) | ((q[3] & 255) << 24);
  int hi = (q[4] & 255) | ((q[5] & 255) << 8) | ((q[6] & 255) << 16) | ((q[7] & 255) << 24);
  ((int2*)(xq + row * DM))[t] = make_int2(lo, hi);
}

// ---- cluster: 16 MFMA 32x32x32 (ks-outer, 2mt x 2nt inner; same-acc 4 apart)
template <int MO>
__device__ __forceinline__ void cluster32(const v4i (&af)[2][4], const v4i (&bf)[2][4],
                                          v16i (&acc)[4][2]) {
  __builtin_amdgcn_s_setprio(1);
#pragma unroll
  for (int ks = 0; ks < 4; ++ks)
#pragma unroll
    for (int m = 0; m < 2; ++m)
#pragma unroll
      for (int n = 0; n < 2; ++n)
        acc[MO + m][n] = __builtin_amdgcn_mfma_i32_32x32x32_i8(
            af[m][ks], bf[n][ks], acc[MO + m][n], 0, 0, 0);
  __builtin_amdgcn_s_setprio(0);
}

// ---- int8 GEMM, 256x256 tile, BK=128B, 8 waves 2x4, mfma_i32_32x32x32_i8 ----
// r18 = r14's rotated race-safe schedule + PAIRED-LINE LDS layout (r12's
// proven zero-conflict scheme, re-derived for 128B rows):
//   byte(r,j) = (r>>1)*256 + ((((r&1)<<3) | (j ^ ((r>>1)&7))) << 4)
// Staging source carries the exact inverse (thread t -> row 2(t>>4)+((t>>3)&1),
// col16 (t&7)^((t>>4)&7)); fragment reads audit to uniform 8 lanes/bank-quad
// (b128 floor). 32x32 shape = 4404 vs 3944 TOPS (-11.6% matrix-pipe cycles).
template <int K, int N, int EPI>
__global__ __launch_bounds__(512, 2) void gemm8_i8_k(
    const int8_t* __restrict__ A, const int8_t* __restrict__ B,
    const float* __restrict__ rowInv, const float* __restrict__ invswp,
    short* __restrict__ Y16, float* __restrict__ Out) {
  constexpr int NT = K / 128;
  constexpr int NBX = N / 256;
  __shared__ __align__(16) uint8_t lds[131072];

  const int t = threadIdx.x;
  const int wave = t >> 6;
  const int lane = t & 63;
  const int wr = wave >> 2;   // 0..1 (128-row half of A)
  const int wc = wave & 3;    // 0..3 (64-col quarter of B)
  const int l31 = lane & 31, kg = lane >> 5;

  // bijective XCD swizzle (gridDim.x % 8 == 0)
  const int cpx = (int)gridDim.x >> 3;
  const int bid0 = blockIdx.x;
  const int bid = (bid0 & 7) * cpx + (bid0 >> 3);
  const int bx = bid % NBX, by = bid / NBX;
  const long arow0 = (long)by * 256;
  const long bcol0 = (long)bx * 256;

  const int8_t* Ablk = A + arow0 * K;
  const int8_t* Bblk = B + bcol0 * K;

  // staging inverse map (paired-line layout): thread t stages dest t*16 (+8192)
  const int srow = 2 * (t >> 4) + ((t >> 3) & 1);              // 0..63
  const int scol = ((t & 7) ^ ((t >> 4) & 7)) << 4;            // inverse col

  // fragment read constants: byte = base + mt/nt*4096 + rb + cks[j]
  const int rb = (l31 >> 1) * 256 + (l31 & 1) * 128;
  const int sx = (l31 >> 1) & 7;
  const int rA = (wr << 14) + rb;
  const int rB = 32768 + ((wc >> 1) << 14) + ((wc & 1) << 13) + rb;
  int cks[4];
#pragma unroll
  for (int ks = 0; ks < 4; ++ks) cks[ks] = (((ks << 1) | kg) ^ sx) << 4;

  v16i acc[4][2] = {};
  v4i a_lo[2][4], a_hi[2][4], b_all[2][4];

#define STAGE(ktile_, part_)                                                      \
  do {                                                                            \
    const int kk = (ktile_);                                                      \
    if (kk < NT) {                                                                \
      uint8_t* d0 = lds + ((kk & 1) << 16) + ((part_) << 14) + (wave << 10);      \
      const int8_t* sp = ((part_) < 2) ? Ablk : Bblk;                             \
      const int8_t* s0 =                                                          \
          sp + (long)((((part_) & 1) << 7) + srow) * K + ((long)kk << 7) + scol;  \
      gload_lds16(s0, d0);                                                        \
      gload_lds16(s0 + ((long)K << 6), d0 + 8192);                                \
    }                                                                             \
  } while (0)

#define SB __builtin_amdgcn_sched_barrier(0)
#define WAIT_LGKM8  asm volatile("s_waitcnt lgkmcnt(8)"  ::: "memory"); SB
#define WAIT_LGKM0  asm volatile("s_waitcnt lgkmcnt(0)"  ::: "memory"); SB
#define WAIT_VM4    asm volatile("s_waitcnt vmcnt(4)"    ::: "memory"); SB
#define WAIT_VM0    asm volatile("s_waitcnt vmcnt(0)"    ::: "memory"); SB

  // prologue: A(0),B(0) + A(1); vmcnt(4) -> A(0),B(0) landed; barrier -> visible;
  // pre-read a_lo(0).
  STAGE(0, 0); STAGE(0, 1); STAGE(0, 2); STAGE(0, 3);
  STAGE(1, 0); STAGE(1, 1);
  WAIT_VM4;
  __builtin_amdgcn_s_barrier();
#pragma unroll
  for (int m = 0; m < 2; ++m)
#pragma unroll
    for (int ks = 0; ks < 4; ++ks)
      a_lo[m][ks] = *(const v4i*)(lds + rA + m * 4096 + cks[ks]);
  SB;

  for (int kt = 0; kt < NT; ++kt) {
    const uint8_t* sA = lds + ((kt & 1) << 16);
    const uint8_t* sB = sA;  // rB carries the +32768
    const uint8_t* sAn = lds + (((kt + 1) & 1) << 16);

    // top: issue b_all (8), a_hi (8); stage B(kt+1)
#pragma unroll
    for (int n = 0; n < 2; ++n)
#pragma unroll
      for (int ks = 0; ks < 4; ++ks)
        b_all[n][ks] = *(const v4i*)(sB + rB + n * 4096 + cks[ks]);
    SB;
#pragma unroll
    for (int m = 0; m < 2; ++m)
#pragma unroll
      for (int ks = 0; ks < 4; ++ks)
        a_hi[m][ks] = *(const v4i*)(sA + rA + (m + 2) * 4096 + cks[ks]);
    SB;
    STAGE(kt + 1, 2);
    STAGE(kt + 1, 3);
    SB;
    WAIT_LGKM8;                       // pre-read a_lo + b_all ready (a_hi may lag)
    cluster32<0>(a_lo, b_all, acc);   // C_lo: mt0,1 x nt0,1 x ks0..3
    WAIT_VM4;                         // own A(kt+1) staging landed
    WAIT_LGKM0;                       // own a_hi reads done (current-A drained)
    __builtin_amdgcn_s_barrier();     // A(kt+1) visible; A region free
    if (kt + 1 < NT) {
#pragma unroll
      for (int m = 0; m < 2; ++m)
#pragma unroll
        for (int ks = 0; ks < 4; ++ks)
          a_lo[m][ks] = *(const v4i*)(sAn + rA + m * 4096 + cks[ks]);
      SB;
    }
    STAGE(kt + 2, 0);
    STAGE(kt + 2, 1);
    SB;
    cluster32<2>(a_hi, b_all, acc);   // C_hi: mt2,3 x nt0,1 x ks0..3
    if (kt < NT - 2) {
      WAIT_VM4;
    } else {
      WAIT_VM0;
    }
    __builtin_amdgcn_s_barrier();
  }

  if constexpr (EPI == 1) {
    // integer-only epilogue: clamp -> LDS short[256][256] (XOR swizzle) -> 16B stores
    __syncthreads();
#pragma unroll
    for (int mt = 0; mt < 4; ++mt) {
#pragma unroll
      for (int r = 0; r < 16; ++r) {
        const int row = wr * 128 + mt * 32 + (r & 3) + 8 * (r >> 2) + 4 * kg;
#pragma unroll
        for (int nt = 0; nt < 2; ++nt) {
          int yi = acc[mt][nt][r];
          int ys = yi < -32767 ? -32767 : (yi > 32767 ? 32767 : yi);
          const int col = wc * 64 + nt * 32 + l31;
          *(short*)(lds + ((row * 512 + col * 2) ^ ((row & 7) << 4))) = (short)ys;
        }
      }
    }
    __syncthreads();
    const int row = t >> 1;
    const int half = t & 1;
    short* gp = Y16 + (arow0 + row) * (long)DF + bcol0 + half * 128;
#pragma unroll
    for (int i = 0; i < 16; ++i) {
      v8s yv = *(const v8s*)(lds + ((row * 512 + half * 256 + i * 16) ^ ((row & 7) << 4)));
      *(v8s*)(gp + i * 8) = yv;
    }
  } else {
    const float invsw = invswp[0];
#pragma unroll
    for (int mt = 0; mt < 4; ++mt) {
#pragma unroll
      for (int r = 0; r < 16; ++r) {
        const long grow = arow0 + wr * 128 + mt * 32 + (r & 3) + 8 * (r >> 2) + 4 * kg;
        const float c2 = rowInv[grow] * invsw;
#pragma unroll
        for (int nt = 0; nt < 2; ++nt)
          Out[grow * N + bcol0 + wc * 64 + nt * 32 + l31] = (float)acc[mt][nt][r] * c2;
      }
    }
  }
#undef STAGE
#undef SB
#undef WAIT_LGKM8
#undef WAIT_LGKM0
#undef WAIT_VM4
#undef WAIT_VM0
}

// ---- quant_h: two-pass per row; silu into 32 registers + block max, then quantize.
__global__ __launch_bounds__(256) void quant_h_k(const short* __restrict__ Y16,
                                                 const float* __restrict__ inv_sx,
                                                 const float* __restrict__ sc,
                                                 int8_t* __restrict__ hq,
                                                 float* __restrict__ inv_sh) {
  const int t = threadIdx.x;
  const long row = blockIdx.x;
  const float c1 = inv_sx[row] * sc[1];
  const v8s* yp = (const v8s*)(Y16 + row * DF);
  float h[32];
  float mx = 0.f;
#pragma unroll
  for (int b = 0; b < 4; ++b) {
    v8s s8 = yp[b * 256 + t];
#pragma unroll
    for (int j = 0; j < 8; ++j) {
      float hv = silu_f((float)s8[j] * c1);
      h[b * 8 + j] = hv;
      mx = fmaxf(mx, fabsf(hv));
    }
  }
#pragma unroll
  for (int d = 1; d < 64; d <<= 1) mx = fmaxf(mx, __shfl_xor(mx, d, 64));
  __shared__ float wm[4];
  if ((t & 63) == 0) wm[t >> 6] = mx;
  __syncthreads();
  const float m = fmaxf(fmaxf(wm[0], wm[1]), fmaxf(wm[2], wm[3]));
  const float scale = 127.0f / fmaxf(m, 1e-5f);
  if (t == 0) inv_sh[row] = 1.0f / scale;
  int2* op = (int2*)(hq + row * DF);
#pragma unroll
  for (int b = 0; b < 4; ++b) {
    int q[8];
#pragma unroll
    for (int j = 0; j < 8; ++j) {
      int qq = (int)rintf(h[b * 8 + j] * scale);
      q[j] = qq < -128 ? -128 : (qq > 127 ? 127 : qq);
    }
    int lo = (q[0] & 255) | ((q[1] & 255) << 8) | ((q[2] & 255) << 16) | ((q[3] & 255) << 24);
    int hi = (q[4] & 255) | ((q[5] & 255) << 8) | ((q[6] & 255) << 16) | ((q[7] & 255) << 24);
    op[b * 256 + t] = make_int2(lo, hi);
  }
}

extern "C" void kernel_launch(void* const* d_in, const int* in_sizes, int n_in,
                              void* d_out, int out_size, void* d_ws, size_t ws_size,
                              hipStream_t stream) {
  const float* x = (const float*)d_in[0];
  const float* W1 = (const float*)d_in[1];
  const float* W2 = (const float*)d_in[2];
  float* out = (float*)d_out;

  uint8_t* w = (uint8_t*)d_ws;
  float* sc = (float*)(w + 0);
  float* partial = (float*)(w + 256);
  float* inv_sx = (float*)(w + 8448);
  float* inv_sh = (float*)(w + 8448 + 65536);
  uint8_t* w1q = w + 8448 + 131072 + 4194304;
  uint8_t* w2q = w1q + 16777216;
  uint8_t* xq = w2q + 16777216;
  uint8_t* hq = xq + 33554432;
  short* y16 = (short*)(hq + 134217728);

  abs_sum_k<<<dim3(1024, 2), 256, 0, stream>>>(W1, W2, partial);
  finalize_scales_k<<<2, 256, 0, stream>>>(partial, sc);
  tern_quant_k<<<dim3(16384, 2), 256, 0, stream>>>(W1, W2, (int8_t*)w1q, (int8_t*)w2q, sc);
  act_quant_x_k<<<16384, 256, 0, stream>>>(x, (int8_t*)xq, inv_sx);
  // GEMM1: [16384,2048] x [8192,2048]^T -> y16 (integer-only epilogue)
  gemm8_i8_k<2048, 8192, 1><<<2048, 512, 0, stream>>>(
      (const int8_t*)xq, (const int8_t*)w1q, nullptr, nullptr, y16, nullptr);
  quant_h_k<<<16384, 256, 0, stream>>>(y16, inv_sx, sc, (int8_t*)hq, inv_sh);
  // GEMM2: [16384,8192] x [2048,8192]^T -> out
  gemm8_i8_k<8192, 2048, 0><<<512, 512, 0, stream>>>(
      (const int8_t*)hq, (const int8_t*)w2q, inv_sh, sc + 3, nullptr, out);
}

// Round 19
// 761.252 us; speedup vs baseline: 1.1037x; 1.1037x over previous
//
#include <hip/hip_runtime.h>
#include <hip/hip_bf16.h>
#include <cstdint>

#define DM 2048
#define DF 8192

typedef int v4i __attribute__((ext_vector_type(4)));
typedef short v8s __attribute__((ext_vector_type(8)));

__device__ __forceinline__ float silu_f(float y) {
  return y * (1.0f / (1.0f + expf(-y)));
}

__device__ __forceinline__ void gload_lds16(const void* g, void* l) {
  __builtin_amdgcn_global_load_lds(
      (const __attribute__((address_space(1))) void*)g,
      (__attribute__((address_space(3))) void*)l, 16, 0, 0);
}

// ---- stage 1: sum |w| partials; blockIdx.y selects W1/W2 (merged launch) ----
__global__ __launch_bounds__(256) void abs_sum_k(const float* __restrict__ w1,
                                                 const float* __restrict__ w2,
                                                 float* __restrict__ partial) {
  const int t = threadIdx.x;
  const float* w = blockIdx.y ? w2 : w1;
  const float4* wp = (const float4*)w;
  const long base = (long)blockIdx.x * 4096;
  float s = 0.f;
#pragma unroll
  for (int i = 0; i < 16; ++i) {
    float4 v = wp[base + i * 256 + t];
    s += fabsf(v.x) + fabsf(v.y) + fabsf(v.z) + fabsf(v.w);
  }
#pragma unroll
  for (int d = 1; d < 64; d <<= 1) s += __shfl_xor(s, d, 64);
  __shared__ float wsum[4];
  if ((t & 63) == 0) wsum[t >> 6] = s;
  __syncthreads();
  if (t == 0) partial[blockIdx.y * 1024 + blockIdx.x] = (wsum[0] + wsum[1]) + (wsum[2] + wsum[3]);
}

// ---- stage 2: finalize weight scales. sc[0]=sw1, sc[1]=1/sw1, sc[2]=sw2, sc[3]=1/sw2 ----
__global__ __launch_bounds__(256) void finalize_scales_k(const float* __restrict__ partial,
                                                         float* __restrict__ sc) {
  const float* p = partial + blockIdx.x * 1024;
  const int t = threadIdx.x;
  float s = (p[t] + p[t + 256]) + (p[t + 512] + p[t + 768]);
#pragma unroll
  for (int d = 1; d < 64; d <<= 1) s += __shfl_xor(s, d, 64);
  __shared__ float wsum[4];
  if ((t & 63) == 0) wsum[t >> 6] = s;
  __syncthreads();
  if (t == 0) {
    float total = (wsum[0] + wsum[1]) + (wsum[2] + wsum[3]);
    float mean = total * (1.0f / 16777216.0f);
    float c = fmaxf(mean, 1e-5f);
    sc[blockIdx.x * 2 + 0] = 1.0f / c;
    sc[blockIdx.x * 2 + 1] = c;
  }
}

// ---- ternary weight quantization; blockIdx.y selects W1/W2 (merged launch) ----
__global__ __launch_bounds__(256) void tern_quant_k(const float* __restrict__ w1,
                                                    const float* __restrict__ w2,
                                                    int8_t* __restrict__ wq1,
                                                    int8_t* __restrict__ wq2,
                                                    const float* __restrict__ sc) {
  const float* w = blockIdx.y ? w2 : w1;
  int8_t* wq = blockIdx.y ? wq2 : wq1;
  const float s = sc[blockIdx.y * 2];
  const long i = (long)blockIdx.x * 256 + threadIdx.x;
  float4 v = ((const float4*)w)[i];
  int q0 = (int)rintf(v.x * s); q0 = q0 < -1 ? -1 : (q0 > 1 ? 1 : q0);
  int q1 = (int)rintf(v.y * s); q1 = q1 < -1 ? -1 : (q1 > 1 ? 1 : q1);
  int q2 = (int)rintf(v.z * s); q2 = q2 < -1 ? -1 : (q2 > 1 ? 1 : q2);
  int q3 = (int)rintf(v.w * s); q3 = q3 < -1 ? -1 : (q3 > 1 ? 1 : q3);
  ((int*)wq)[i] = (q0 & 255) | ((q1 & 255) << 8) | ((q2 & 255) << 16) | ((q3 & 255) << 24);
}

// ---- per-token activation quant of x ----
__global__ __launch_bounds__(256) void act_quant_x_k(const float* __restrict__ x,
                                                     int8_t* __restrict__ xq,
                                                     float* __restrict__ inv_sx) {
  const int t = threadIdx.x;
  const long row = blockIdx.x;
  const float4* xr = (const float4*)(x + row * DM);
  float4 v0 = xr[t * 2], v1 = xr[t * 2 + 1];
  float m = fmaxf(fmaxf(fmaxf(fabsf(v0.x), fabsf(v0.y)), fmaxf(fabsf(v0.z), fabsf(v0.w))),
                  fmaxf(fmaxf(fabsf(v1.x), fabsf(v1.y)), fmaxf(fabsf(v1.z), fabsf(v1.w))));
#pragma unroll
  for (int d = 1; d < 64; d <<= 1) m = fmaxf(m, __shfl_xor(m, d, 64));
  __shared__ float wm[4];
  if ((t & 63) == 0) wm[t >> 6] = m;
  __syncthreads();
  m = fmaxf(fmaxf(wm[0], wm[1]), fmaxf(wm[2], wm[3]));
  const float scale = 127.0f / fmaxf(m, 1e-5f);
  if (t == 0) inv_sx[row] = 1.0f / scale;
  float vv[8] = {v0.x, v0.y, v0.z, v0.w, v1.x, v1.y, v1.z, v1.w};
  int q[8];
#pragma unroll
  for (int j = 0; j < 8; ++j) {
    int qq = (int)rintf(vv[j] * scale);
    q[j] = qq < -128 ? -128 : (qq > 127 ? 127 : qq);
  }
  int lo = (q[0] & 255) | ((q[1] & 255) << 8) | ((q[2] & 255) << 16) | ((q[3] & 255) << 24);
  int hi = (q[4] & 255) | ((q[5] & 255) << 8) | ((q[6] & 255) << 16) | ((q[7] & 255) << 24);
  ((int2*)(xq + row * DM))[t] = make_int2(lo, hi);
}

// ---- cluster: 16 MFMA (4m x 2n x 2ks), ks-outer so same-acc writes are 8 apart
template <int MO, int NO>
__device__ __forceinline__ void cluster(const v4i (&af)[4][2], const v4i (&bf)[2][2],
                                        v4i (&acc)[8][4]) {
  __builtin_amdgcn_s_setprio(1);
#pragma unroll
  for (int ks = 0; ks < 2; ++ks)
#pragma unroll
    for (int m = 0; m < 4; ++m)
#pragma unroll
      for (int n = 0; n < 2; ++n)
        acc[MO + m][NO + n] = __builtin_amdgcn_mfma_i32_16x16x64_i8(
            af[m][ks], bf[n][ks], acc[MO + m][NO + n], 0, 0, 0);
  __builtin_amdgcn_s_setprio(0);
}

// ---- int8 GEMM, 256x256 tile, BK=128B, 8 waves 2x4, mfma_i32_16x16x64_i8 ----
// Best-measured structure (761.9 us total): rotated race-safe schedule,
// unpinned — compiler interleaves ds_read/MFMA with fine lgkmcnt(N).
// Counted vmcnt protocol, WAIT_LGKM0 before the mid barrier, plain XCD
// swizzle + plain L2-allocated stores (the only proven-good write path).
// Measured-dead-end alternatives: 8-phase (r2), 32x32 shape (r14/r18),
// TLP multi-block (r12/r13), B-direct (r16), supertile/nt-stores (r7/r8).
template <int K, int N, int EPI>
__global__ __launch_bounds__(512, 2) void gemm8_i8_k(
    const int8_t* __restrict__ A, const int8_t* __restrict__ B,
    const float* __restrict__ rowInv, const float* __restrict__ invswp,
    short* __restrict__ Y16, float* __restrict__ Out) {
  constexpr int NT = K / 128;
  constexpr int NBX = N / 256;
  __shared__ __align__(16) uint8_t lds[131072];

  const int t = threadIdx.x;
  const int wave = t >> 6;
  const int lane = t & 63;
  const int wr = wave >> 2;   // 0..1
  const int wc = wave & 3;    // 0..3
  const int l15 = lane & 15, l4 = lane >> 4;

  // bijective XCD swizzle (gridDim.x % 8 == 0)
  const int cpx = (int)gridDim.x >> 3;
  const int bid0 = blockIdx.x;
  const int bid = (bid0 & 7) * cpx + (bid0 >> 3);
  const int bx = bid % NBX, by = bid / NBX;
  const long arow0 = (long)by * 256;
  const long bcol0 = (long)bx * 256;

  const int8_t* Ablk = A + arow0 * K;
  const int8_t* Bblk = B + bcol0 * K;

  const int srow = t >> 3;
  const int scol = ((t & 7) ^ (srow & 7)) << 4;

  const int rAo = (wr * 128 + l15) * 128;
  const int rBo = (wc * 64 + l15) * 128;
  const int sw = (l15 & 7) << 4;
  const int cc0 = (l4 * 16) ^ sw;
  const int cc1 = (64 | (l4 * 16)) ^ sw;

  v4i acc[8][4] = {};
  v4i a_lo[4][2], a_hi[4][2], b_lo[2][2], b_hi[2][2];

#define STAGE(ktile_, part_)                                                      \
  do {                                                                            \
    const int kk = (ktile_);                                                      \
    if (kk < NT) {                                                                \
      uint8_t* d0 = lds + ((kk & 1) << 16) + ((part_) << 14) + (wave << 10);      \
      const int8_t* sp = ((part_) < 2) ? Ablk : Bblk;                             \
      const int8_t* s0 =                                                          \
          sp + (long)((((part_) & 1) << 7) + srow) * K + ((long)kk << 7) + scol;  \
      gload_lds16(s0, d0);                                                        \
      gload_lds16(s0 + ((long)K << 6), d0 + 8192);                                \
    }                                                                             \
  } while (0)

#define FENCE       asm volatile("" ::: "memory")
#define WAIT_LGKM0  asm volatile("s_waitcnt lgkmcnt(0)"  ::: "memory")
#define WAIT_VM4    asm volatile("s_waitcnt vmcnt(4)"    ::: "memory")
#define WAIT_VM0    asm volatile("s_waitcnt vmcnt(0)"    ::: "memory")

  // prologue: A(0),B(0) + A(1); vmcnt(4) -> A(0),B(0) landed; barrier -> visible;
  // pre-read a_lo(0).
  STAGE(0, 0); STAGE(0, 1); STAGE(0, 2); STAGE(0, 3);
  STAGE(1, 0); STAGE(1, 1);
  WAIT_VM4;
  __builtin_amdgcn_s_barrier();
  FENCE;
  {
    const uint8_t* sA0 = lds;
#pragma unroll
    for (int m = 0; m < 4; ++m) {
      a_lo[m][0] = *(const v4i*)(sA0 + rAo + m * 2048 + cc0);
      a_lo[m][1] = *(const v4i*)(sA0 + rAo + m * 2048 + cc1);
    }
  }

  for (int kt = 0; kt < NT; ++kt) {
    const uint8_t* sA = lds + ((kt & 1) << 16);
    const uint8_t* sB = sA + 32768;
    const uint8_t* sAn = lds + (((kt + 1) & 1) << 16);

    // issue all current-tile reads; compiler interleaves with MFMAs below,
    // inserting fine-grained lgkmcnt(N) at first use of each fragment.
#pragma unroll
    for (int n = 0; n < 2; ++n) {
      b_lo[n][0] = *(const v4i*)(sB + rBo + n * 2048 + cc0);
      b_lo[n][1] = *(const v4i*)(sB + rBo + n * 2048 + cc1);
    }
#pragma unroll
    for (int n = 0; n < 2; ++n) {
      b_hi[n][0] = *(const v4i*)(sB + rBo + (n + 2) * 2048 + cc0);
      b_hi[n][1] = *(const v4i*)(sB + rBo + (n + 2) * 2048 + cc1);
    }
#pragma unroll
    for (int m = 0; m < 4; ++m) {
      a_hi[m][0] = *(const v4i*)(sA + rAo + (m + 4) * 2048 + cc0);
      a_hi[m][1] = *(const v4i*)(sA + rAo + (m + 4) * 2048 + cc1);
    }
    STAGE(kt + 1, 2);   // B(kt+1) -> other buffer (readers crossed last barrier)
    STAGE(kt + 1, 3);
    cluster<0, 0>(a_lo, b_lo, acc);   // C_ll (a_lo pre-read; b_lo via auto-wait)
    cluster<0, 2>(a_lo, b_hi, acc);   // C_lh (a_lo registers now free)
    WAIT_VM4;                         // own A(kt+1) staging writes landed
    WAIT_LGKM0;                       // own current-A reads drained
    __builtin_amdgcn_s_barrier();     // => A(kt+1) globally visible; A region free
    FENCE;
    if (kt + 1 < NT) {
#pragma unroll
      for (int m = 0; m < 4; ++m) {   // pre-read a_lo(kt+1), overlaps MFMA tail
        a_lo[m][0] = *(const v4i*)(sAn + rAo + m * 2048 + cc0);
        a_lo[m][1] = *(const v4i*)(sAn + rAo + m * 2048 + cc1);
      }
    }
    STAGE(kt + 2, 0);                 // A(kt+2) -> current buffer A region
    STAGE(kt + 2, 1);
    cluster<4, 0>(a_hi, b_lo, acc);   // C_hl
    cluster<4, 2>(a_hi, b_hi, acc);   // C_hh
    if (kt < NT - 2) {
      WAIT_VM4;                       // B(kt+1) landed (own); A(kt+2) in flight
    } else {
      WAIT_VM0;
    }
    __builtin_amdgcn_s_barrier();
    FENCE;
  }

  if constexpr (EPI == 1) {
    // integer-only epilogue: clamp -> LDS short[256][256] (XOR swizzle) -> 16B stores
    __syncthreads();
#pragma unroll
    for (int mi = 0; mi < 8; ++mi) {
#pragma unroll
      for (int r = 0; r < 4; ++r) {
        const int row = wr * 128 + mi * 16 + l4 * 4 + r;
#pragma unroll
        for (int ni = 0; ni < 4; ++ni) {
          int yi = acc[mi][ni][r];
          int ys = yi < -32767 ? -32767 : (yi > 32767 ? 32767 : yi);
          const int col = wc * 64 + ni * 16 + l15;
          *(short*)(lds + ((row * 512 + col * 2) ^ ((row & 7) << 4))) = (short)ys;
        }
      }
    }
    __syncthreads();
    const int row = t >> 1;
    const int half = t & 1;
    short* gp = Y16 + (arow0 + row) * (long)DF + bcol0 + half * 128;
#pragma unroll
    for (int i = 0; i < 16; ++i) {
      v8s yv = *(const v8s*)(lds + ((row * 512 + half * 256 + i * 16) ^ ((row & 7) << 4)));
      *(v8s*)(gp + i * 8) = yv;
    }
  } else {
    const float invsw = invswp[0];
#pragma unroll
    for (int mi = 0; mi < 8; ++mi) {
#pragma unroll
      for (int r = 0; r < 4; ++r) {
        const long grow = arow0 + wr * 128 + mi * 16 + l4 * 4 + r;
        const float c2 = rowInv[grow] * invsw;
#pragma unroll
        for (int ni = 0; ni < 4; ++ni)
          Out[grow * N + bcol0 + wc * 64 + ni * 16 + l15] = (float)acc[mi][ni][r] * c2;
      }
    }
  }
#undef STAGE
#undef FENCE
#undef WAIT_LGKM0
#undef WAIT_VM4
#undef WAIT_VM0
}

// ---- quant_h: two-pass per row; silu into 32 registers + block max, then quantize.
__global__ __launch_bounds__(256) void quant_h_k(const short* __restrict__ Y16,
                                                 const float* __restrict__ inv_sx,
                                                 const float* __restrict__ sc,
                                                 int8_t* __restrict__ hq,
                                                 float* __restrict__ inv_sh) {
  const int t = threadIdx.x;
  const long row = blockIdx.x;
  const float c1 = inv_sx[row] * sc[1];
  const v8s* yp = (const v8s*)(Y16 + row * DF);
  float h[32];
  float mx = 0.f;
#pragma unroll
  for (int b = 0; b < 4; ++b) {
    v8s s8 = yp[b * 256 + t];
#pragma unroll
    for (int j = 0; j < 8; ++j) {
      float hv = silu_f((float)s8[j] * c1);
      h[b * 8 + j] = hv;
      mx = fmaxf(mx, fabsf(hv));
    }
  }
#pragma unroll
  for (int d = 1; d < 64; d <<= 1) mx = fmaxf(mx, __shfl_xor(mx, d, 64));
  __shared__ float wm[4];
  if ((t & 63) == 0) wm[t >> 6] = mx;
  __syncthreads();
  const float m = fmaxf(fmaxf(wm[0], wm[1]), fmaxf(wm[2], wm[3]));
  const float scale = 127.0f / fmaxf(m, 1e-5f);
  if (t == 0) inv_sh[row] = 1.0f / scale;
  int2* op = (int2*)(hq + row * DF);
#pragma unroll
  for (int b = 0; b < 4; ++b) {
    int q[8];
#pragma unroll
    for (int j = 0; j < 8; ++j) {
      int qq = (int)rintf(h[b * 8 + j] * scale);
      q[j] = qq < -128 ? -128 : (qq > 127 ? 127 : qq);
    }
    int lo = (q[0] & 255) | ((q[1] & 255) << 8) | ((q[2] & 255) << 16) | ((q[3] & 255) << 24);
    int hi = (q[4] & 255) | ((q[5] & 255) << 8) | ((q[6] & 255) << 16) | ((q[7] & 255) << 24);
    op[b * 256 + t] = make_int2(lo, hi);
  }
}

extern "C" void kernel_launch(void* const* d_in, const int* in_sizes, int n_in,
                              void* d_out, int out_size, void* d_ws, size_t ws_size,
                              hipStream_t stream) {
  const float* x = (const float*)d_in[0];
  const float* W1 = (const float*)d_in[1];
  const float* W2 = (const float*)d_in[2];
  float* out = (float*)d_out;

  uint8_t* w = (uint8_t*)d_ws;
  float* sc = (float*)(w + 0);
  float* partial = (float*)(w + 256);           // 2048 floats (2 x 1024)
  float* inv_sx = (float*)(w + 8448);
  float* inv_sh = (float*)(w + 8448 + 65536);
  uint8_t* w1q = w + 8448 + 131072 + 4194304;
  uint8_t* w2q = w1q + 16777216;
  uint8_t* xq = w2q + 16777216;
  uint8_t* hq = xq + 33554432;
  short* y16 = (short*)(hq + 134217728);

  abs_sum_k<<<dim3(1024, 2), 256, 0, stream>>>(W1, W2, partial);
  finalize_scales_k<<<2, 256, 0, stream>>>(partial, sc);
  tern_quant_k<<<dim3(16384, 2), 256, 0, stream>>>(W1, W2, (int8_t*)w1q, (int8_t*)w2q, sc);
  act_quant_x_k<<<16384, 256, 0, stream>>>(x, (int8_t*)xq, inv_sx);
  // GEMM1: [16384,2048] x [8192,2048]^T -> y16 (integer-only epilogue)
  gemm8_i8_k<2048, 8192, 1><<<2048, 512, 0, stream>>>(
      (const int8_t*)xq, (const int8_t*)w1q, nullptr, nullptr, y16, nullptr);
  quant_h_k<<<16384, 256, 0, stream>>>(y16, inv_sx, sc, (int8_t*)hq, inv_sh);
  // GEMM2: [16384,8192] x [2048,8192]^T -> out
  gemm8_i8_k<8192, 2048, 0><<<512, 512, 0, stream>>>(
      (const int8_t*)hq, (const int8_t*)w2q, inv_sh, sc + 3, nullptr, out);
}